// Round 7
// baseline (148.946 us; speedup 1.0000x reference)
//
#include <hip/hip_runtime.h>

typedef unsigned int u32;
typedef unsigned long long u64;

// ---------------------------------------------------------------------------
// Output layout (float32, 414 elems):
//  [0..3] confmat [tn,fp,fn,tp]; [4] map_; [5..105] prec_t; [106..206] rec_t;
//  [207..307] ths; [308..408] spec_t; [409..413] recall,precision,specificity,
//  accuracy, loss_out
//
// Fine histogram: 4096 bins = 102 threshold-aligned regions x 40 sub-bins.
// proc v3: non-divergent binning. k = ceil(p1*100) (no exec-mask fixup loops;
// elements within ~1ulp of a boundary may shift one region: <=~20 elements,
// error ~2.5e-6 on O(1) outputs, far under tolerance). sub is clamped so the
// element stays inside region k regardless of rounding -> internally
// consistent prefix counts.
//
// probe_hist (diagnostic, output-dead): 3 passes of stream + cheap bin +
// ds_add. Launched LAST; writes partials AFTER reduce_hist consumed it.
// Its dur/3 = floor for stream+LDS-atomic at this shape.
//
// Workspace: partials NBLK*K*4 | fineHist K*8 | counters 32B | prefixD K*8 |
//            apPartial APB*8
// ---------------------------------------------------------------------------

#define K     4096
#define NBLK  512
#define TPB   1024
#define APB   256

static __device__ __forceinline__ float safe_div_f(float a, float b) {
    return (b > 0.0f) ? (a / fmaxf(b, 1.0f)) : 0.0f;
}

static __device__ __forceinline__ void proc(
    float l0, float l1, int lbl,
    u32& tp, u32& lblS, u32& predS, u32* __restrict__ fineLDS)
{
    float d = l1 - l0;
    u32 pred = (d > 0.0f) ? 1u : 0u;            // argmax: ties -> 0
    float e = __expf(-fabsf(d));                // in (0,1]
    float pl = e * __builtin_amdgcn_rcpf(1.0f + e);   // min(p1,1-p1)
    float p1 = pred ? (1.0f - pl) : pl;         // in [0,1]

    tp    += ((u32)lbl & pred);
    lblS  += (u32)lbl;
    predS += pred;

    // region k = ceil(p1*100) in [0,100]; sub-bin within region, clamped so
    // the element lands inside region k whatever the rounding. Non-divergent.
    float t100 = p1 * 100.0f;
    int k = (int)ceilf(t100);
    k = min(max(k, 0), 101);
    int sub = (int)((t100 - (float)(k - 1)) * 40.0f);
    sub = min(max(sub, 0), 39);

    atomicAdd(&fineLDS[k * 40 + sub], 1u | ((u32)lbl << 16));
}

__global__ void __launch_bounds__(TPB, 8)
main_pass(const float* __restrict__ logits, const int* __restrict__ targets,
          int N, u32* __restrict__ partials, u32* __restrict__ counters)
{
    __shared__ u32 fineLDS[K];
    __shared__ u32 sConf[3];

    const int t = threadIdx.x;
    for (int i = t; i < K; i += TPB) fineLDS[i] = 0u;
    if (t < 3) sConf[t] = 0u;
    __syncthreads();

    const int nPairs = N >> 1;                   // pair = (float4 logits, int2 tg)
    const int S = NBLK * TPB;
    const float4* __restrict__ lp = (const float4*)logits;
    const int2*   __restrict__ tg = (const int2*)targets;

    u32 tp = 0u, lblS = 0u, predS = 0u;

    int p = blockIdx.x * TPB + t;
    bool v0 = p < nPairs;
    bool v1 = (p + S) < nPairs;

    float4 a0, a1; int2 b0, b1;
    if (v0) { a0 = lp[p];     b0 = tg[p]; }
    if (v1) { a1 = lp[p + S]; b1 = tg[p + S]; }

    while (v0) {
        const int pn = p + 2 * S;
        const bool w0 = pn < nPairs;
        const bool w1 = (pn + S) < nPairs;
        float4 na0, na1; int2 nb0, nb1;
        if (w0) { na0 = lp[pn];     nb0 = tg[pn]; }
        if (w1) { na1 = lp[pn + S]; nb1 = tg[pn + S]; }

        proc(a0.x, a0.y, b0.x, tp, lblS, predS, fineLDS);
        proc(a0.z, a0.w, b0.y, tp, lblS, predS, fineLDS);
        if (v1) {
            proc(a1.x, a1.y, b1.x, tp, lblS, predS, fineLDS);
            proc(a1.z, a1.w, b1.y, tp, lblS, predS, fineLDS);
        }

        a0 = na0; b0 = nb0; a1 = na1; b1 = nb1;
        v0 = w0; v1 = w1; p = pn;
    }

    if (blockIdx.x == 0 && t == 0 && (N & 1)) {
        int last = N - 1;
        proc(logits[2 * last], logits[2 * last + 1], targets[last],
             tp, lblS, predS, fineLDS);
    }

    #pragma unroll
    for (int off = 32; off > 0; off >>= 1) {
        tp    += __shfl_down(tp, off);
        lblS  += __shfl_down(lblS, off);
        predS += __shfl_down(predS, off);
    }
    if ((t & 63) == 0) {
        atomicAdd(&sConf[0], tp);
        atomicAdd(&sConf[1], lblS);
        atomicAdd(&sConf[2], predS);
    }
    __syncthreads();
    if (t < 3 && sConf[t]) atomicAdd(&counters[t], sConf[t]);

    u32* dst = partials + (size_t)blockIdx.x * K;
    for (int i2 = t; i2 < K; i2 += TPB) dst[i2] = fineLDS[i2];
}

// DIAGNOSTIC: 3 passes of stream + cheap-bin + ds_add. Output is dead.
__global__ void __launch_bounds__(TPB, 8)
probe_hist(const float* __restrict__ logits, const int* __restrict__ targets,
           int N, u32* __restrict__ sink)
{
    __shared__ u32 h[K];
    const int t = threadIdx.x;
    for (int i = t; i < K; i += TPB) h[i] = 0u;
    __syncthreads();

    const int nPairs = N >> 1;
    const int S = NBLK * TPB;
    const float4* __restrict__ lp = (const float4*)logits;
    const int2*   __restrict__ tg = (const int2*)targets;

    #pragma unroll 1
    for (int pass = 0; pass < 3; ++pass) {
        for (int p = blockIdx.x * TPB + t; p < nPairs; p += S) {
            float4 a = lp[p];
            int2   b = tg[p];
            float d0 = a.y - a.x;
            float d1 = a.w - a.z;
            u32 u0 = __float_as_uint(d0);
            u32 u1 = __float_as_uint(d1);
            atomicAdd(&h[(u0 >> 13) & (K - 1)], 1u | ((u32)b.x << 16));
            atomicAdd(&h[(u1 >> 13) & (K - 1)], 1u | ((u32)b.y << 16));
        }
    }
    __syncthreads();
    u32* dst = sink + (size_t)blockIdx.x * K;
    for (int i = t; i < K; i += TPB) dst[i] = h[i];
}

// Fold NBLK slices into u64 fineHist. grid = 16 chunks x 8 groups = 128 blocks.
__global__ void __launch_bounds__(256)
reduce_hist(const u32* __restrict__ partials, u64* __restrict__ fineHist)
{
    const int chunk = blockIdx.x & 15;
    const int grp   = blockIdx.x >> 4;          // 0..7, 64 slices each
    const int bin = chunk * 256 + threadIdx.x;
    u32 cnt = 0u, pos = 0u;
    const u32* p = partials + (size_t)(grp * 64) * K + bin;
    #pragma unroll 8
    for (int s = 0; s < 64; ++s) {
        u32 v = p[(size_t)s * K];
        cnt += (v & 0xFFFFu);
        pos += (v >> 16);
    }
    atomicAdd(&fineHist[bin], (u64)cnt | ((u64)pos << 32));
}

// Full exclusive descending prefix of fineHist -> prefixD[d], d=0 highest bin.
__global__ void __launch_bounds__(1024)
scan_full(const u64* __restrict__ fineHist, u64* __restrict__ prefixD)
{
    __shared__ u64 sh[1024];
    const int t = threadIdx.x;
    u64 v0 = fineHist[K - 1 - (4 * t + 0)];
    u64 v1 = fineHist[K - 1 - (4 * t + 1)];
    u64 v2 = fineHist[K - 1 - (4 * t + 2)];
    u64 v3 = fineHist[K - 1 - (4 * t + 3)];
    u64 s0 = v0, s1 = s0 + v1, s2 = s1 + v2, s3 = s2 + v3;
    sh[t] = s3;
    __syncthreads();
    for (int off = 1; off < 1024; off <<= 1) {
        u64 v = (t >= off) ? sh[t - off] : 0ULL;
        __syncthreads();
        sh[t] += v;
        __syncthreads();
    }
    u64 excl = sh[t] - s3;
    prefixD[4 * t + 0] = excl;
    prefixD[4 * t + 1] = excl + s0;
    prefixD[4 * t + 2] = excl + s1;
    prefixD[4 * t + 3] = excl + s2;
}

// AP contributions: one wave per 4 bins, lanes parallelize the j-loop.
__global__ void __launch_bounds__(256)
ap_kernel(const u64* __restrict__ fineHist, const u64* __restrict__ prefixD,
          double* __restrict__ apPartial)
{
    __shared__ double sd[4];
    const int t = threadIdx.x;
    const int lane = t & 63;
    const int wave = t >> 6;
    float acc = 0.0f;
    #pragma unroll
    for (int q = 0; q < 4; ++q) {
        int d = blockIdx.x * 16 + wave * 4 + q;
        u64 h = fineHist[K - 1 - d];
        u32 Cv = (u32)h;
        u32 Pv = (u32)(h >> 32);
        if (Pv) {
            u64 e = prefixD[d];
            float Nb = (float)(u32)e;
            float Pb = (float)(u32)(e >> 32);
            float ratio = (float)Cv / (float)Pv;
            for (u32 j = (u32)lane + 1u; j <= Pv; j += 64u) {
                float jf = (float)j;
                float rank = Nb + (jf - 0.5f) * ratio + 0.5f;
                acc += (Pb + jf) / rank;
            }
        }
    }
    double dacc = (double)acc;
    #pragma unroll
    for (int off = 32; off > 0; off >>= 1)
        dacc += __shfl_down(dacc, off);
    if (lane == 0) sd[wave] = dacc;
    __syncthreads();
    if (t == 0) apPartial[blockIdx.x] = sd[0] + sd[1] + sd[2] + sd[3];
}

__global__ void __launch_bounds__(128)
finalize(const u32* __restrict__ counters, const u64* __restrict__ prefixD,
         const double* __restrict__ apPartial,
         const float* __restrict__ loss, int N, float* __restrict__ out)
{
    __shared__ double sd[128];
    const int t = threadIdx.x;
    sd[t] = apPartial[t] + apPartial[t + 128];
    __syncthreads();
    for (int off = 64; off > 0; off >>= 1) {
        if (t < off) sd[t] += sd[t + off];
        __syncthreads();
    }

    const u32 tpS = counters[0], lblS = counters[1], predS = counters[2];
    const float nF = (float)N;

    if (t <= 100) {
        u64 pv = prefixD[K - (t + 1) * 40];
        float above  = (float)(u32)pv;
        float aboveP = (float)(u32)(pv >> 32);
        float totPos = (float)lblS;
        float idx_f = nF - above;
        float tp_t = aboveP;
        float fn_t = totPos - aboveP;
        float tn_t = idx_f - fn_t;
        float fp_t = nF - idx_f - tp_t;
        out[5 + t]   = safe_div_f(tp_t, tp_t + fp_t);  // prec_t
        out[106 + t] = safe_div_f(tp_t, tp_t + fn_t);  // rec_t
        out[207 + t] = (float)t * 0.01f;               // ths
        out[308 + t] = safe_div_f(tn_t, tn_t + fp_t);  // spec_t
    }

    if (t == 0) {
        float tp0 = (float)tpS;
        float fn0 = (float)(lblS - tpS);
        float fp0 = (float)(predS - tpS);
        float tn0 = (float)((u32)N - lblS - predS + tpS);
        double denom = (lblS > 0u) ? (double)lblS : 1.0;
        out[0] = tn0; out[1] = fp0; out[2] = fn0; out[3] = tp0;
        out[4] = (float)(sd[0] / denom);
        out[409] = safe_div_f(tp0, tp0 + fn0);
        out[410] = safe_div_f(tp0, tp0 + fp0);
        out[411] = safe_div_f(tn0, tn0 + fp0);
        out[412] = (tp0 + tn0) / nF;
        out[413] = (loss[0] + loss[1] + loss[2] + loss[3]) * 0.25f;
    }
}

extern "C" void kernel_launch(void* const* d_in, const int* in_sizes, int n_in,
                              void* d_out, int out_size, void* d_ws, size_t ws_size,
                              hipStream_t stream)
{
    const float* logits  = (const float*)d_in[0];
    const int*   targets = (const int*)d_in[1];
    const float* loss    = (const float*)d_in[2];
    const int N = in_sizes[1];

    char* ws = (char*)d_ws;
    size_t off = 0;
    u32* partials = (u32*)(ws + off);   off += (size_t)NBLK * K * 4;   // 8 MB
    u64* fineHist = (u64*)(ws + off);   off += (size_t)K * 8;          // 32 KB
    u32* counters = (u32*)(ws + off);   off += 32;
    u64* prefixD  = (u64*)(ws + off);   off += (size_t)K * 8;          // 32 KB
    double* apPartial = (double*)(ws + off);                           // 2 KB

    hipMemsetAsync(fineHist, 0, (size_t)K * 8 + 32, stream);

    main_pass<<<NBLK, TPB, 0, stream>>>(logits, targets, N, partials, counters);
    reduce_hist<<<128, 256, 0, stream>>>(partials, fineHist);
    scan_full<<<1, 1024, 0, stream>>>(fineHist, prefixD);
    ap_kernel<<<APB, 256, 0, stream>>>(fineHist, prefixD, apPartial);
    finalize<<<1, 128, 0, stream>>>(counters, prefixD, apPartial, loss, N, (float*)d_out);
    // diagnostic probe LAST (partials already consumed; output-dead)
    probe_hist<<<NBLK, TPB, 0, stream>>>(logits, targets, N, partials);
}

// Round 8
// 101.688 us; speedup vs baseline: 1.4647x; 1.4647x over previous
//
#include <hip/hip_runtime.h>
#include <math.h>

typedef unsigned int u32;
typedef unsigned long long u64;

// ---------------------------------------------------------------------------
// Output layout (float32, 414 elems):
//  [0..3] confmat [tn,fp,fn,tp]; [4] map_; [5..105] prec_t; [106..206] rec_t;
//  [207..307] ths; [308..408] spec_t; [409..413] recall,precision,specificity,
//  accuracy, loss_out
//
// Strategy (round 8): bin on d = l1-l0 directly (monotone in p1 = sigmoid(d)).
// 4096 linear bins of width 1/256 over d in [-8,8] (clamped). A per-bin LUT
// {split, base} places elements EXACTLY w.r.t. the 101 threshold boundaries:
// d_k = largest f32 d with sigmoid(d) <= th_k (double-precision bisection,
// setup kernel). Each bin contains at most ONE boundary (spacing >= 0.04 >
// 2x bin width). slot = base + (d > split); slots are ascending in d with
// region boundaries exactly at slot edges -> threshold counts = prefix sums.
// Confusion matrix from slot prefix at k=50 boundary (d<=0 <-> pred=0).
// Per element: ~13 VALU + ds_read_b64 + ds_add  (probe-validated regime:
// stream+LDS-atomic floor = 28-30us/pass at this shape).
//
// Workspace: partials NBLK*NSLOT*4 | fineHist NSLOT*8 | prefixA NSLOT*8 |
//            lutG 4096*8 | dBound 101*4(pad) | slotK 101*4(pad) | apPartial
// ---------------------------------------------------------------------------

#define NBIN  4096
#define NSLOT 5120
#define NBLK  512
#define TPB   1024
#define APB   320

static __device__ __forceinline__ float safe_div_f(float a, float b) {
    return (b > 0.0f) ? (a / fmaxf(b, 1.0f)) : 0.0f;
}

// bin index of a float d (saturating, matches main-pass element binning)
static __device__ __forceinline__ int bin_of(float d) {
    float t = d * 256.0f;
    t = fminf(fmaxf(t, -1.0e9f), 1.0e9f);
    int b = (int)floorf(t) + 2048;
    return min(max(b, 0), NBIN - 1);
}

// --- setup 1: exact f32 threshold boundaries in d-space ---------------------
__global__ void __launch_bounds__(128)
setup_bounds(float* __restrict__ dBound)
{
    int k = threadIdx.x;
    if (k > 100) return;
    if (k == 0)   { dBound[0]   = -1.0e30f; return; }  // p1 <= 0.00: nothing
    if (k == 100) { dBound[100] =  1.0e30f; return; }  // p1 <= 1.00: all
    double thd = (double)((float)k * 0.01f);
    float lo = -16.0f, hi = 16.0f;      // invariant: sig(lo)<=th < sig(hi)
    for (int i = 0; i < 64; ++i) {
        float mid = 0.5f * (lo + hi);
        double p = 1.0 / (1.0 + exp(-(double)mid));
        if (p <= thd) lo = mid; else hi = mid;
    }
    dBound[k] = lo;                     // largest f32 d with sigmoid(d) <= th
}

// --- setup 2: per-bin LUT {split,base} and per-threshold slot index ---------
__global__ void __launch_bounds__(1024)
setup_lut(const float* __restrict__ dBound, u64* __restrict__ lutG,
          u32* __restrict__ slotK)
{
    int b = blockIdx.x * 1024 + threadIdx.x;       // 0..4095
    int nb = 0;
    float split = 1.0e38f;                          // no boundary in bin
    for (int k = 0; k <= 100; ++k) {
        int bk = bin_of(dBound[k]);
        nb += (bk < b) ? 1 : 0;
        if (bk == b) split = dBound[k];             // at most one per bin
    }
    lutG[b] = ((u64)(u32)(b + nb) << 32) | (u64)__float_as_uint(split);

    if (b <= 100) {
        int bk = bin_of(dBound[b]);
        int nb2 = 0;
        for (int k = 0; k <= 100; ++k) nb2 += (bin_of(dBound[k]) < bk) ? 1 : 0;
        slotK[b] = (u32)(bk + nb2);                 // low-slot of boundary bin
    }
}

// --- main pass: probe-lean stream + LUT bin + LDS atomic --------------------
__global__ void __launch_bounds__(TPB, 8)
main_pass(const float* __restrict__ logits, const int* __restrict__ targets,
          int N, const u64* __restrict__ lutG, u32* __restrict__ partials)
{
    __shared__ u64 lutLDS[NBIN];    // 32 KB
    __shared__ u32 hist[NSLOT];     // 20 KB

    const int t = threadIdx.x;
    for (int i = t; i < NBIN; i += TPB) lutLDS[i] = lutG[i];
    for (int i = t; i < NSLOT; i += TPB) hist[i] = 0u;
    __syncthreads();

    const int nPairs = N >> 1;
    const float4* __restrict__ lp = (const float4*)logits;
    const int2*   __restrict__ tg = (const int2*)targets;

    for (int p = blockIdx.x * TPB + t; p < nPairs; p += NBLK * TPB) {
        float4 a = lp[p];
        int2   b = tg[p];
        float d0 = a.y - a.x;
        float d1 = a.w - a.z;
        int b0 = min(max((int)floorf(d0 * 256.0f) + 2048, 0), NBIN - 1);
        int b1 = min(max((int)floorf(d1 * 256.0f) + 2048, 0), NBIN - 1);
        u64 e0 = lutLDS[b0];
        u64 e1 = lutLDS[b1];
        u32 s0 = (u32)(e0 >> 32) + ((d0 > __uint_as_float((u32)e0)) ? 1u : 0u);
        u32 s1 = (u32)(e1 >> 32) + ((d1 > __uint_as_float((u32)e1)) ? 1u : 0u);
        atomicAdd(&hist[s0], 1u | ((u32)b.x << 16));
        atomicAdd(&hist[s1], 1u | ((u32)b.y << 16));
    }
    // odd-N tail (N even here; generality)
    if (blockIdx.x == 0 && t == 0 && (N & 1)) {
        int x = N - 1;
        float d = logits[2 * x + 1] - logits[2 * x];
        int bb = min(max((int)floorf(d * 256.0f) + 2048, 0), NBIN - 1);
        u64 e = lutLDS[bb];
        u32 s = (u32)(e >> 32) + ((d > __uint_as_float((u32)e)) ? 1u : 0u);
        atomicAdd(&hist[s], 1u | ((u32)targets[x] << 16));
    }
    __syncthreads();

    u32* dst = partials + (size_t)blockIdx.x * NSLOT;
    for (int i = t; i < NSLOT; i += TPB) dst[i] = hist[i];
}

// --- fold NBLK slices -> u64 fineHist (count | pos<<32) ---------------------
__global__ void __launch_bounds__(256)
reduce_hist(const u32* __restrict__ partials, u64* __restrict__ fineHist)
{
    const int chunk = blockIdx.x % 20;          // 20 chunks x 256 slots
    const int grp   = blockIdx.x / 20;          // 8 groups x 64 slices
    const int s = chunk * 256 + threadIdx.x;
    u32 cnt = 0u, pos = 0u;
    const u32* p = partials + (size_t)(grp * 64) * NSLOT + s;
    #pragma unroll 8
    for (int i = 0; i < 64; ++i) {
        u32 v = p[(size_t)i * NSLOT];
        cnt += (v & 0xFFFFu);
        pos += (v >> 16);
    }
    atomicAdd(&fineHist[s], (u64)cnt | ((u64)pos << 32));
}

// --- ascending inclusive prefix over NSLOT slots ----------------------------
__global__ void __launch_bounds__(1024)
scan_full(const u64* __restrict__ fineHist, u64* __restrict__ prefixA)
{
    __shared__ u64 sh[1024];
    const int t = threadIdx.x;
    u64 v0 = fineHist[5 * t + 0];
    u64 v1 = fineHist[5 * t + 1];
    u64 v2 = fineHist[5 * t + 2];
    u64 v3 = fineHist[5 * t + 3];
    u64 v4 = fineHist[5 * t + 4];
    u64 s0 = v0, s1 = s0 + v1, s2 = s1 + v2, s3 = s2 + v3, s4 = s3 + v4;
    sh[t] = s4;
    __syncthreads();
    for (int off = 1; off < 1024; off <<= 1) {
        u64 v = (t >= off) ? sh[t - off] : 0ULL;
        __syncthreads();
        sh[t] += v;
        __syncthreads();
    }
    u64 excl = sh[t] - s4;
    prefixA[5 * t + 0] = excl + s0;
    prefixA[5 * t + 1] = excl + s1;
    prefixA[5 * t + 2] = excl + s2;
    prefixA[5 * t + 3] = excl + s3;
    prefixA[5 * t + 4] = excl + s4;
}

// --- AP contributions; stride-APB slot interleave for load balance ----------
__global__ void __launch_bounds__(256)
ap_kernel(const u64* __restrict__ fineHist, const u64* __restrict__ prefixA,
          double* __restrict__ apPartial)
{
    __shared__ double sd[4];
    const int t = threadIdx.x;
    const int lane = t & 63;
    const int wave = t >> 6;
    const u64 tot = prefixA[NSLOT - 1];
    const float Ntot = (float)(u32)tot;
    const float Ptot = (float)(u32)(tot >> 32);
    float acc = 0.0f;
    #pragma unroll
    for (int q = 0; q < 4; ++q) {
        int s = blockIdx.x + (wave * 4 + q) * APB;  // interleaved hot/cold
        u64 h = fineHist[s];
        u32 Cv = (u32)h;
        u32 Pv = (u32)(h >> 32);
        if (Pv) {
            u64 inc = prefixA[s];
            float Nb = Ntot - (float)(u32)inc;          // strictly above
            float Pb = Ptot - (float)(u32)(inc >> 32);  // positives above
            float ratio = (float)Cv / (float)Pv;
            for (u32 j = (u32)lane + 1u; j <= Pv; j += 64u) {
                float jf = (float)j;
                float rank = Nb + (jf - 0.5f) * ratio + 0.5f;
                acc += (Pb + jf) / rank;
            }
        }
    }
    double dacc = (double)acc;
    #pragma unroll
    for (int off = 32; off > 0; off >>= 1)
        dacc += __shfl_down(dacc, off);
    if (lane == 0) sd[wave] = dacc;
    __syncthreads();
    if (t == 0) apPartial[blockIdx.x] = sd[0] + sd[1] + sd[2] + sd[3];
}

// --- finalize ----------------------------------------------------------------
__global__ void __launch_bounds__(512)
finalize(const u64* __restrict__ prefixA, const u32* __restrict__ slotK,
         const double* __restrict__ apPartial,
         const float* __restrict__ loss, float* __restrict__ out)
{
    __shared__ double sd[512];
    const int t = threadIdx.x;
    sd[t] = (t < APB) ? apPartial[t] : 0.0;
    __syncthreads();
    for (int off = 256; off > 0; off >>= 1) {
        if (t < off) sd[t] += sd[t + off];
        __syncthreads();
    }

    const u64 tot = prefixA[NSLOT - 1];
    const u32 Ncnt = (u32)tot;
    const u32 Pcnt = (u32)(tot >> 32);

    if (t <= 100) {
        u64 pv = prefixA[slotK[t]];         // exact count/pos with p1 <= th_t
        float idx_f = (float)(u32)pv;
        float fn_t  = (float)(u32)(pv >> 32);
        float tp_t  = (float)Pcnt - fn_t;
        float tn_t  = idx_f - fn_t;
        float fp_t  = (float)Ncnt - idx_f - tp_t;
        out[5 + t]   = safe_div_f(tp_t, tp_t + fp_t);  // prec_t
        out[106 + t] = safe_div_f(tp_t, tp_t + fn_t);  // rec_t
        out[207 + t] = (float)t * 0.01f;               // ths
        out[308 + t] = safe_div_f(tn_t, tn_t + fp_t);  // spec_t
    }

    if (t == 0) {
        u64 pv50 = prefixA[slotK[50]];      // d <= 0  <=>  pred = 0
        u32 lowC = (u32)pv50, lowP = (u32)(pv50 >> 32);
        float tp0 = (float)(Pcnt - lowP);
        float fn0 = (float)lowP;
        float tn0 = (float)(lowC - lowP);
        float fp0 = (float)(Ncnt - lowC) - tp0;
        float nF  = (float)Ncnt;
        out[0] = tn0; out[1] = fp0; out[2] = fn0; out[3] = tp0;
        double denom = (Pcnt > 0u) ? (double)Pcnt : 1.0;
        out[4] = (float)(sd[0] / denom);
        out[409] = safe_div_f(tp0, tp0 + fn0);
        out[410] = safe_div_f(tp0, tp0 + fp0);
        out[411] = safe_div_f(tn0, tn0 + fp0);
        out[412] = (tp0 + tn0) / nF;
        out[413] = (loss[0] + loss[1] + loss[2] + loss[3]) * 0.25f;
    }
}

extern "C" void kernel_launch(void* const* d_in, const int* in_sizes, int n_in,
                              void* d_out, int out_size, void* d_ws, size_t ws_size,
                              hipStream_t stream)
{
    const float* logits  = (const float*)d_in[0];
    const int*   targets = (const int*)d_in[1];
    const float* loss    = (const float*)d_in[2];
    const int N = in_sizes[1];

    char* ws = (char*)d_ws;
    size_t off = 0;
    u32* partials = (u32*)(ws + off);   off += (size_t)NBLK * NSLOT * 4; // 10.5 MB
    u64* fineHist = (u64*)(ws + off);   off += (size_t)NSLOT * 8;        // 40 KB
    u64* prefixA  = (u64*)(ws + off);   off += (size_t)NSLOT * 8;        // 40 KB
    u64* lutG     = (u64*)(ws + off);   off += (size_t)NBIN * 8;         // 32 KB
    float* dBound = (float*)(ws + off); off += 512;
    u32* slotK    = (u32*)(ws + off);   off += 512;
    double* apPartial = (double*)(ws + off);                             // 2.5 KB

    hipMemsetAsync(fineHist, 0, (size_t)NSLOT * 8, stream);

    setup_bounds<<<1, 128, 0, stream>>>(dBound);
    setup_lut<<<NBIN / 1024, 1024, 0, stream>>>(dBound, lutG, slotK);
    main_pass<<<NBLK, TPB, 0, stream>>>(logits, targets, N, lutG, partials);
    reduce_hist<<<160, 256, 0, stream>>>(partials, fineHist);
    scan_full<<<1, 1024, 0, stream>>>(fineHist, prefixA);
    ap_kernel<<<APB, 256, 0, stream>>>(fineHist, prefixA, apPartial);
    finalize<<<1, 512, 0, stream>>>(prefixA, slotK, apPartial, loss, (float*)d_out);
}

// Round 9
// 72.229 us; speedup vs baseline: 2.0621x; 1.4079x over previous
//
#include <hip/hip_runtime.h>
#include <math.h>

typedef unsigned int u32;
typedef unsigned long long u64;

// ---------------------------------------------------------------------------
// Output layout (float32, 414 elems):
//  [0..3] confmat [tn,fp,fn,tp]; [4] map_; [5..105] prec_t; [106..206] rec_t;
//  [207..307] ths; [308..408] spec_t; [409..413] recall,precision,specificity,
//  accuracy, loss_out
//
// Round 9: probe-minimal main pass. bin = clamp(floor(d*256)+2048, 0, 4095),
// d = l1-l0 (monotone in p1 = sigmoid(d)). Histogram u32 packed count|pos<<16
// per block in LDS, flushed non-atomically. Downstream:
//  - confmat: prefix at bin 2048 (d>0 <=> pred=1; exact ties ~0 elements).
//  - threshold counts: prefix + fractional interpolation at d_k = logit(th_k)
//    (double log in finalize). Interp error ~tens of elements << 2% tol.
//  - AP: per-bin uniform-rank approximation (validated rounds 3-8).
// Probe (round 7) measured this exact stream+LDS-atomic structure at
// ~30us/pass; main_pass adds ~3 VALU over the probe.
//
// Workspace: partials NBLK*NBIN*4 (8MB) | fineHist NBIN*8 | prefixA NBIN*8 |
//            apPartial APB*8
// ---------------------------------------------------------------------------

#define NBIN  4096
#define NBLK  512
#define TPB   1024
#define APB   256

static __device__ __forceinline__ float safe_div_f(float a, float b) {
    return (b > 0.0f) ? (a / fmaxf(b, 1.0f)) : 0.0f;
}

__global__ void __launch_bounds__(TPB, 8)
main_pass(const float* __restrict__ logits, const int* __restrict__ targets,
          int N, u32* __restrict__ partials)
{
    __shared__ u32 hist[NBIN];      // 16 KB
    const int t = threadIdx.x;
    for (int i = t; i < NBIN; i += TPB) hist[i] = 0u;
    __syncthreads();

    const int nPairs = N >> 1;
    const float4* __restrict__ lp = (const float4*)logits;
    const int2*   __restrict__ tg = (const int2*)targets;

    for (int p = blockIdx.x * TPB + t; p < nPairs; p += NBLK * TPB) {
        float4 a = lp[p];
        int2   b = tg[p];
        float x0 = fminf(fmaxf(fmaf(a.y - a.x, 256.0f, 2048.0f), 0.0f), 4095.0f);
        float x1 = fminf(fmaxf(fmaf(a.w - a.z, 256.0f, 2048.0f), 0.0f), 4095.0f);
        atomicAdd(&hist[(int)x0], 1u | ((u32)b.x << 16));
        atomicAdd(&hist[(int)x1], 1u | ((u32)b.y << 16));
    }
    // odd-N tail (N even here; generality)
    if (blockIdx.x == 0 && t == 0 && (N & 1)) {
        int x = N - 1;
        float d = logits[2 * x + 1] - logits[2 * x];
        float xb = fminf(fmaxf(fmaf(d, 256.0f, 2048.0f), 0.0f), 4095.0f);
        atomicAdd(&hist[(int)xb], 1u | ((u32)targets[x] << 16));
    }
    __syncthreads();

    u32* dst = partials + (size_t)blockIdx.x * NBIN;
    for (int i = t; i < NBIN; i += TPB) dst[i] = hist[i];
}

// Fold NBLK slices into u64 fineHist. grid = 16 chunks x 8 groups = 128 blocks.
__global__ void __launch_bounds__(256)
reduce_hist(const u32* __restrict__ partials, u64* __restrict__ fineHist)
{
    const int chunk = blockIdx.x & 15;          // 16 chunks x 256 bins
    const int grp   = blockIdx.x >> 4;          // 8 groups x 64 slices
    const int s = chunk * 256 + threadIdx.x;
    u32 cnt = 0u, pos = 0u;
    const u32* p = partials + (size_t)(grp * 64) * NBIN + s;
    #pragma unroll 8
    for (int i = 0; i < 64; ++i) {
        u32 v = p[(size_t)i * NBIN];
        cnt += (v & 0xFFFFu);
        pos += (v >> 16);
    }
    atomicAdd(&fineHist[s], (u64)cnt | ((u64)pos << 32));
}

// Ascending inclusive prefix over NBIN bins.
__global__ void __launch_bounds__(1024)
scan_full(const u64* __restrict__ fineHist, u64* __restrict__ prefixA)
{
    __shared__ u64 sh[1024];
    const int t = threadIdx.x;
    u64 v0 = fineHist[4 * t + 0];
    u64 v1 = fineHist[4 * t + 1];
    u64 v2 = fineHist[4 * t + 2];
    u64 v3 = fineHist[4 * t + 3];
    u64 s0 = v0, s1 = s0 + v1, s2 = s1 + v2, s3 = s2 + v3;
    sh[t] = s3;
    __syncthreads();
    for (int off = 1; off < 1024; off <<= 1) {
        u64 v = (t >= off) ? sh[t - off] : 0ULL;
        __syncthreads();
        sh[t] += v;
        __syncthreads();
    }
    u64 excl = sh[t] - s3;
    prefixA[4 * t + 0] = excl + s0;
    prefixA[4 * t + 1] = excl + s1;
    prefixA[4 * t + 2] = excl + s2;
    prefixA[4 * t + 3] = excl + s3;
}

// AP contributions; stride-APB bin interleave balances hot center bins.
__global__ void __launch_bounds__(256)
ap_kernel(const u64* __restrict__ fineHist, const u64* __restrict__ prefixA,
          double* __restrict__ apPartial)
{
    __shared__ double sd[4];
    const int t = threadIdx.x;
    const int lane = t & 63;
    const int wave = t >> 6;
    const u64 tot = prefixA[NBIN - 1];
    const float Ntot = (float)(u32)tot;
    const float Ptot = (float)(u32)(tot >> 32);
    float acc = 0.0f;
    #pragma unroll
    for (int q = 0; q < 4; ++q) {
        int s = blockIdx.x + (wave * 4 + q) * APB;   // 16 x 256 = 4096
        u64 h = fineHist[s];
        u32 Cv = (u32)h;
        u32 Pv = (u32)(h >> 32);
        if (Pv) {
            u64 inc = prefixA[s];
            float Nb = Ntot - (float)(u32)inc;          // strictly above (desc)
            float Pb = Ptot - (float)(u32)(inc >> 32);  // positives above
            float ratio = (float)Cv / (float)Pv;
            for (u32 j = (u32)lane + 1u; j <= Pv; j += 64u) {
                float jf = (float)j;
                float rank = Nb + (jf - 0.5f) * ratio + 0.5f;
                acc += (Pb + jf) / rank;
            }
        }
    }
    double dacc = (double)acc;
    #pragma unroll
    for (int off = 32; off > 0; off >>= 1)
        dacc += __shfl_down(dacc, off);
    if (lane == 0) sd[wave] = dacc;
    __syncthreads();
    if (t == 0) apPartial[blockIdx.x] = sd[0] + sd[1] + sd[2] + sd[3];
}

__global__ void __launch_bounds__(128)
finalize(const u64* __restrict__ fineHist, const u64* __restrict__ prefixA,
         const double* __restrict__ apPartial,
         const float* __restrict__ loss, float* __restrict__ out)
{
    __shared__ double sd[128];
    const int t = threadIdx.x;
    sd[t] = apPartial[t] + apPartial[t + 128];
    __syncthreads();
    for (int off = 64; off > 0; off >>= 1) {
        if (t < off) sd[t] += sd[t + off];
        __syncthreads();
    }

    const u64 tot = prefixA[NBIN - 1];
    const u32 Ncnt = (u32)tot;
    const u32 Pcnt = (u32)(tot >> 32);

    if (t <= 100) {
        // boundary position in bin space: x = logit(th)*256 + 2048
        double th = (double)((float)t * 0.01f);
        double x  = log(th / (1.0 - th)) * 256.0 + 2048.0;   // -inf/+inf ok
        x = fmin(fmax(x, 0.0), 4096.0);
        int bk = (int)x; if (bk > NBIN - 1) bk = NBIN - 1;
        double frac = x - (double)bk;
        u64 ex = (bk > 0) ? prefixA[bk - 1] : 0ULL;
        u64 h  = fineHist[bk];
        double cb = (double)(u32)ex + frac * (double)(u32)h;          // count p1<=th
        double pb = (double)(u32)(ex >> 32) + frac * (double)(u32)(h >> 32);
        float idx_f = (float)cb;
        float fn_t  = (float)pb;
        float tp_t  = (float)Pcnt - fn_t;
        float tn_t  = idx_f - fn_t;
        float fp_t  = (float)Ncnt - idx_f - tp_t;
        out[5 + t]   = safe_div_f(tp_t, tp_t + fp_t);  // prec_t
        out[106 + t] = safe_div_f(tp_t, tp_t + fn_t);  // rec_t
        out[207 + t] = (float)t * 0.01f;               // ths
        out[308 + t] = safe_div_f(tn_t, tn_t + fp_t);  // spec_t
    }

    if (t == 0) {
        u64 pv = prefixA[2047];             // d < 0  (bin 2048 starts at d=0)
        u32 lowC = (u32)pv, lowP = (u32)(pv >> 32);
        float tp0 = (float)(Pcnt - lowP);
        float fn0 = (float)lowP;
        float tn0 = (float)(lowC - lowP);
        float fp0 = (float)(Ncnt - lowC) - tp0;
        float nF  = (float)Ncnt;
        out[0] = tn0; out[1] = fp0; out[2] = fn0; out[3] = tp0;
        double denom = (Pcnt > 0u) ? (double)Pcnt : 1.0;
        out[4] = (float)(sd[0] / denom);
        out[409] = safe_div_f(tp0, tp0 + fn0);
        out[410] = safe_div_f(tp0, tp0 + fp0);
        out[411] = safe_div_f(tn0, tn0 + fp0);
        out[412] = (tp0 + tn0) / nF;
        out[413] = (loss[0] + loss[1] + loss[2] + loss[3]) * 0.25f;
    }
}

extern "C" void kernel_launch(void* const* d_in, const int* in_sizes, int n_in,
                              void* d_out, int out_size, void* d_ws, size_t ws_size,
                              hipStream_t stream)
{
    const float* logits  = (const float*)d_in[0];
    const int*   targets = (const int*)d_in[1];
    const float* loss    = (const float*)d_in[2];
    const int N = in_sizes[1];

    char* ws = (char*)d_ws;
    size_t off = 0;
    u32* partials = (u32*)(ws + off);   off += (size_t)NBLK * NBIN * 4;  // 8 MB
    u64* fineHist = (u64*)(ws + off);   off += (size_t)NBIN * 8;         // 32 KB
    u64* prefixA  = (u64*)(ws + off);   off += (size_t)NBIN * 8;         // 32 KB
    double* apPartial = (double*)(ws + off);                             // 2 KB

    hipMemsetAsync(fineHist, 0, (size_t)NBIN * 8, stream);

    main_pass<<<NBLK, TPB, 0, stream>>>(logits, targets, N, partials);
    reduce_hist<<<128, 256, 0, stream>>>(partials, fineHist);
    scan_full<<<1, 1024, 0, stream>>>(fineHist, prefixA);
    ap_kernel<<<APB, 256, 0, stream>>>(fineHist, prefixA, apPartial);
    finalize<<<1, 128, 0, stream>>>(fineHist, prefixA, apPartial, loss, (float*)d_out);
}

// Round 10
// 66.521 us; speedup vs baseline: 2.2391x; 1.0858x over previous
//
#include <hip/hip_runtime.h>
#include <math.h>

typedef unsigned int u32;
typedef unsigned long long u64;

// ---------------------------------------------------------------------------
// Output layout (float32, 414 elems):
//  [0..3] confmat [tn,fp,fn,tp]; [4] map_; [5..105] prec_t; [106..206] rec_t;
//  [207..307] ths; [308..408] spec_t; [409..413] recall,precision,specificity,
//  accuracy, loss_out
//
// Round 10 = round 3's load shape (8 elems / 6 indep loads per iter — the only
// main-loop shape that hit 63us) x round 9's lean d-bin hash (5 VALU: fma,
// min, max, cvt; bin = clamp(floor(d*256)+2048)) x round 9's tail
// (interpolated thresholds at d_k = logit(th_k), confmat at bin-2048 edge,
// per-bin uniform AP ranks; validated absmax 3.8e-6).
//
// Workspace: partials NBLK*NBIN*4 (8MB) | fineHist NBIN*8 | prefixA NBIN*8 |
//            apPartial APB*8
// ---------------------------------------------------------------------------

#define NBIN  4096
#define NBLK  512
#define TPB   1024
#define APB   256

static __device__ __forceinline__ float safe_div_f(float a, float b) {
    return (b > 0.0f) ? (a / fmaxf(b, 1.0f)) : 0.0f;
}

static __device__ __forceinline__ int bin5(float d0, float d1) {
    float x = fminf(fmaxf(fmaf(d1 - d0, 256.0f, 2048.0f), 0.0f), 4095.0f);
    return (int)x;
}

__global__ void __launch_bounds__(TPB, 8)
main_pass(const float* __restrict__ logits, const int* __restrict__ targets,
          int N, u32* __restrict__ partials)
{
    __shared__ u32 hist[NBIN];      // 16 KB
    const int t = threadIdx.x;
    for (int i = t; i < NBIN; i += TPB) hist[i] = 0u;
    __syncthreads();

    const int nQuad = N >> 2;                     // quad = 2 float4 + 1 int4
    const int gid = blockIdx.x * TPB + t;
    const int stride = NBLK * TPB;
    const float4* __restrict__ lp = (const float4*)logits;  // lp[2q],lp[2q+1]
    const int4*   __restrict__ tg = (const int4*)targets;   // tg[q]

    int i = gid;
    // 8 elements per iteration: 6 independent loads in flight, bins computed
    // before the atomic cluster.
    for (; i + stride < nQuad; i += 2 * stride) {
        const int j = i + stride;
        float4 a0 = lp[2 * i];
        float4 b0 = lp[2 * i + 1];
        int4   t0 = tg[i];
        float4 a1 = lp[2 * j];
        float4 b1 = lp[2 * j + 1];
        int4   t1 = tg[j];
        int s0 = bin5(a0.x, a0.y), s1 = bin5(a0.z, a0.w);
        int s2 = bin5(b0.x, b0.y), s3 = bin5(b0.z, b0.w);
        int s4 = bin5(a1.x, a1.y), s5 = bin5(a1.z, a1.w);
        int s6 = bin5(b1.x, b1.y), s7 = bin5(b1.z, b1.w);
        atomicAdd(&hist[s0], 1u | ((u32)t0.x << 16));
        atomicAdd(&hist[s1], 1u | ((u32)t0.y << 16));
        atomicAdd(&hist[s2], 1u | ((u32)t0.z << 16));
        atomicAdd(&hist[s3], 1u | ((u32)t0.w << 16));
        atomicAdd(&hist[s4], 1u | ((u32)t1.x << 16));
        atomicAdd(&hist[s5], 1u | ((u32)t1.y << 16));
        atomicAdd(&hist[s6], 1u | ((u32)t1.z << 16));
        atomicAdd(&hist[s7], 1u | ((u32)t1.w << 16));
    }
    for (; i < nQuad; i += stride) {
        float4 a0 = lp[2 * i];
        float4 b0 = lp[2 * i + 1];
        int4   t0 = tg[i];
        int s0 = bin5(a0.x, a0.y), s1 = bin5(a0.z, a0.w);
        int s2 = bin5(b0.x, b0.y), s3 = bin5(b0.z, b0.w);
        atomicAdd(&hist[s0], 1u | ((u32)t0.x << 16));
        atomicAdd(&hist[s1], 1u | ((u32)t0.y << 16));
        atomicAdd(&hist[s2], 1u | ((u32)t0.z << 16));
        atomicAdd(&hist[s3], 1u | ((u32)t0.w << 16));
    }
    if (blockIdx.x == 0 && t == 0) {
        for (int x = nQuad << 2; x < N; ++x) {
            int s = bin5(logits[2 * x], logits[2 * x + 1]);
            atomicAdd(&hist[s], 1u | ((u32)targets[x] << 16));
        }
    }
    __syncthreads();

    u32* dst = partials + (size_t)blockIdx.x * NBIN;
    for (int i2 = t; i2 < NBIN; i2 += TPB) dst[i2] = hist[i2];
}

// Fold NBLK slices into u64 fineHist. grid = 16 chunks x 8 groups = 128 blocks.
__global__ void __launch_bounds__(256)
reduce_hist(const u32* __restrict__ partials, u64* __restrict__ fineHist)
{
    const int chunk = blockIdx.x & 15;          // 16 chunks x 256 bins
    const int grp   = blockIdx.x >> 4;          // 8 groups x 64 slices
    const int s = chunk * 256 + threadIdx.x;
    u32 cnt = 0u, pos = 0u;
    const u32* p = partials + (size_t)(grp * 64) * NBIN + s;
    #pragma unroll 8
    for (int i = 0; i < 64; ++i) {
        u32 v = p[(size_t)i * NBIN];
        cnt += (v & 0xFFFFu);
        pos += (v >> 16);
    }
    atomicAdd(&fineHist[s], (u64)cnt | ((u64)pos << 32));
}

// Ascending inclusive prefix over NBIN bins.
__global__ void __launch_bounds__(1024)
scan_full(const u64* __restrict__ fineHist, u64* __restrict__ prefixA)
{
    __shared__ u64 sh[1024];
    const int t = threadIdx.x;
    u64 v0 = fineHist[4 * t + 0];
    u64 v1 = fineHist[4 * t + 1];
    u64 v2 = fineHist[4 * t + 2];
    u64 v3 = fineHist[4 * t + 3];
    u64 s0 = v0, s1 = s0 + v1, s2 = s1 + v2, s3 = s2 + v3;
    sh[t] = s3;
    __syncthreads();
    for (int off = 1; off < 1024; off <<= 1) {
        u64 v = (t >= off) ? sh[t - off] : 0ULL;
        __syncthreads();
        sh[t] += v;
        __syncthreads();
    }
    u64 excl = sh[t] - s3;
    prefixA[4 * t + 0] = excl + s0;
    prefixA[4 * t + 1] = excl + s1;
    prefixA[4 * t + 2] = excl + s2;
    prefixA[4 * t + 3] = excl + s3;
}

// AP contributions; stride-APB bin interleave balances hot center bins.
__global__ void __launch_bounds__(256)
ap_kernel(const u64* __restrict__ fineHist, const u64* __restrict__ prefixA,
          double* __restrict__ apPartial)
{
    __shared__ double sd[4];
    const int t = threadIdx.x;
    const int lane = t & 63;
    const int wave = t >> 6;
    const u64 tot = prefixA[NBIN - 1];
    const float Ntot = (float)(u32)tot;
    const float Ptot = (float)(u32)(tot >> 32);
    float acc = 0.0f;
    #pragma unroll
    for (int q = 0; q < 4; ++q) {
        int s = blockIdx.x + (wave * 4 + q) * APB;   // 16 x 256 = 4096
        u64 h = fineHist[s];
        u32 Cv = (u32)h;
        u32 Pv = (u32)(h >> 32);
        if (Pv) {
            u64 inc = prefixA[s];
            float Nb = Ntot - (float)(u32)inc;          // strictly above (desc)
            float Pb = Ptot - (float)(u32)(inc >> 32);  // positives above
            float ratio = (float)Cv / (float)Pv;
            for (u32 j = (u32)lane + 1u; j <= Pv; j += 64u) {
                float jf = (float)j;
                float rank = Nb + (jf - 0.5f) * ratio + 0.5f;
                acc += (Pb + jf) * __builtin_amdgcn_rcpf(rank);
            }
        }
    }
    double dacc = (double)acc;
    #pragma unroll
    for (int off = 32; off > 0; off >>= 1)
        dacc += __shfl_down(dacc, off);
    if (lane == 0) sd[wave] = dacc;
    __syncthreads();
    if (t == 0) apPartial[blockIdx.x] = sd[0] + sd[1] + sd[2] + sd[3];
}

__global__ void __launch_bounds__(128)
finalize(const u64* __restrict__ fineHist, const u64* __restrict__ prefixA,
         const double* __restrict__ apPartial,
         const float* __restrict__ loss, float* __restrict__ out)
{
    __shared__ double sd[128];
    const int t = threadIdx.x;
    sd[t] = apPartial[t] + apPartial[t + 128];
    __syncthreads();
    for (int off = 64; off > 0; off >>= 1) {
        if (t < off) sd[t] += sd[t + off];
        __syncthreads();
    }

    const u64 tot = prefixA[NBIN - 1];
    const u32 Ncnt = (u32)tot;
    const u32 Pcnt = (u32)(tot >> 32);

    if (t <= 100) {
        // boundary position in bin space: x = logit(th)*256 + 2048
        double th = (double)((float)t * 0.01f);
        double x  = log(th / (1.0 - th)) * 256.0 + 2048.0;   // -inf/+inf ok
        x = fmin(fmax(x, 0.0), 4096.0);
        int bk = (int)x; if (bk > NBIN - 1) bk = NBIN - 1;
        double frac = x - (double)bk;
        u64 ex = (bk > 0) ? prefixA[bk - 1] : 0ULL;
        u64 h  = fineHist[bk];
        double cb = (double)(u32)ex + frac * (double)(u32)h;          // count p1<=th
        double pb = (double)(u32)(ex >> 32) + frac * (double)(u32)(h >> 32);
        float idx_f = (float)cb;
        float fn_t  = (float)pb;
        float tp_t  = (float)Pcnt - fn_t;
        float tn_t  = idx_f - fn_t;
        float fp_t  = (float)Ncnt - idx_f - tp_t;
        out[5 + t]   = safe_div_f(tp_t, tp_t + fp_t);  // prec_t
        out[106 + t] = safe_div_f(tp_t, tp_t + fn_t);  // rec_t
        out[207 + t] = (float)t * 0.01f;               // ths
        out[308 + t] = safe_div_f(tn_t, tn_t + fp_t);  // spec_t
    }

    if (t == 0) {
        u64 pv = prefixA[2047];             // d < 0  (bin 2048 starts at d=0)
        u32 lowC = (u32)pv, lowP = (u32)(pv >> 32);
        float tp0 = (float)(Pcnt - lowP);
        float fn0 = (float)lowP;
        float tn0 = (float)(lowC - lowP);
        float fp0 = (float)(Ncnt - lowC) - tp0;
        float nF  = (float)Ncnt;
        out[0] = tn0; out[1] = fp0; out[2] = fn0; out[3] = tp0;
        double denom = (Pcnt > 0u) ? (double)Pcnt : 1.0;
        out[4] = (float)(sd[0] / denom);
        out[409] = safe_div_f(tp0, tp0 + fn0);
        out[410] = safe_div_f(tp0, tp0 + fp0);
        out[411] = safe_div_f(tn0, tn0 + fp0);
        out[412] = (tp0 + tn0) / nF;
        out[413] = (loss[0] + loss[1] + loss[2] + loss[3]) * 0.25f;
    }
}

extern "C" void kernel_launch(void* const* d_in, const int* in_sizes, int n_in,
                              void* d_out, int out_size, void* d_ws, size_t ws_size,
                              hipStream_t stream)
{
    const float* logits  = (const float*)d_in[0];
    const int*   targets = (const int*)d_in[1];
    const float* loss    = (const float*)d_in[2];
    const int N = in_sizes[1];

    char* ws = (char*)d_ws;
    size_t off = 0;
    u32* partials = (u32*)(ws + off);   off += (size_t)NBLK * NBIN * 4;  // 8 MB
    u64* fineHist = (u64*)(ws + off);   off += (size_t)NBIN * 8;         // 32 KB
    u64* prefixA  = (u64*)(ws + off);   off += (size_t)NBIN * 8;         // 32 KB
    double* apPartial = (double*)(ws + off);                             // 2 KB

    hipMemsetAsync(fineHist, 0, (size_t)NBIN * 8, stream);

    main_pass<<<NBLK, TPB, 0, stream>>>(logits, targets, N, partials);
    reduce_hist<<<128, 256, 0, stream>>>(partials, fineHist);
    scan_full<<<1, 1024, 0, stream>>>(fineHist, prefixA);
    ap_kernel<<<APB, 256, 0, stream>>>(fineHist, prefixA, apPartial);
    finalize<<<1, 128, 0, stream>>>(fineHist, prefixA, apPartial, loss, (float*)d_out);
}